// Round 11
// baseline (125.695 us; speedup 1.0000x reference)
//
#include <hip/hip_runtime.h>
#include <hip/hip_bf16.h>

typedef __attribute__((ext_vector_type(8))) short bf16x8;
typedef __attribute__((ext_vector_type(4))) float f32x4;

#define D_K    256
#define WH     784
#define WHH    392
#define P_REAL 511
#define P_PAD  512
#define C_OUT  200
#define NLEAF  512
#define TDEPTH 9

#define NT      64
#define NTILES  7           // 7*64 >= 392 (tail clamped to duplicate columns)
#define TILE_USH (64*256)   // 32 KB per buffer

// workspace offsets (bytes)
#define WS_PB   0                          // 512*256*2   = 262144
#define WS_P2   262144                     // 512*4
#define WS_DS   264192                     // 512*200*4
#define WS_PM   673792                     // 128*2*512*4
// total 1198080

static __device__ __forceinline__ unsigned short f2bf(float x) {
    union { float f; unsigned int u; } v; v.f = x;
    unsigned int r = v.u + 0x7FFFu + ((v.u >> 16) & 1u);   // RNE
    return (unsigned short)(r >> 16);
}

// --- fused prep (proto -> bf16(-2p) + p2) and softmax(leaf_params) --------
__global__ __launch_bounds__(64)
void prep2_kernel(const float* __restrict__ protos, const float* __restrict__ lp,
                  unsigned short* __restrict__ pb, float* __restrict__ p2,
                  float* __restrict__ ds) {
    int bid = blockIdx.x;
    int l = threadIdx.x;
    if (bid < P_PAD) {
        int p = bid;
        f32x4 v = {0.f, 0.f, 0.f, 0.f};
        if (p < P_REAL)
            v = *reinterpret_cast<const f32x4*>(protos + (size_t)p * D_K + 4 * l);
        ushort4 w;
        w.x = f2bf(-2.f * v[0]); w.y = f2bf(-2.f * v[1]);
        w.z = f2bf(-2.f * v[2]); w.w = f2bf(-2.f * v[3]);
        *reinterpret_cast<ushort4*>(pb + (size_t)p * D_K + 4 * l) = w;
        float s = v[0]*v[0] + v[1]*v[1] + v[2]*v[2] + v[3]*v[3];
#pragma unroll
        for (int m = 32; m >= 1; m >>= 1) s += __shfl_xor(s, m, 64);
        if (l == 0) p2[p] = s;
    } else {
        int row = bid - P_PAD;
        float v[4];
        float mx = -3.4e38f;
#pragma unroll
        for (int i = 0; i < 4; ++i) {
            int c = l + 64 * i;
            v[i] = (c < C_OUT) ? lp[(size_t)row * C_OUT + c] : -3.4e38f;
            mx = fmaxf(mx, v[i]);
        }
#pragma unroll
        for (int m = 32; m >= 1; m >>= 1) mx = fmaxf(mx, __shfl_xor(mx, m, 64));
        float sum = 0.f;
#pragma unroll
        for (int i = 0; i < 4; ++i) {
            int c = l + 64 * i;
            if (c < C_OUT) { v[i] = expf(v[i] - mx); sum += v[i]; }
        }
#pragma unroll
        for (int m = 32; m >= 1; m >>= 1) sum += __shfl_xor(sum, m, 64);
        float inv = 1.f / sum;
#pragma unroll
        for (int i = 0; i < 4; ++i) {
            int c = l + 64 * i;
            if (c < C_OUT) ds[(size_t)row * C_OUT + c] = v[i] * inv;
        }
    }
}

// --- main: read-once fused distance+min, NT=64 (7 barriers vs 13) ---------
// grid 256 = 128 b x 2 wh-halves, 512 threads (8 waves), 1 block/CU.
// Each wave holds 64 p-rows (af[4][8]); 8 waves = all 512 protos -> each
// block streams its xs half exactly once. Tile = 64 cols x 256 k, staged in
// two 32-col halves reusing ONE ld[4] register set (R7's exact budget, no
// spill). Conflict-reduced XOR key (n ^ n>>2)&7 on both write & read sides.
__global__ __launch_bounds__(512, 2)
void proto_min_kernel(const float* __restrict__ xs,
                      const unsigned short* __restrict__ pb,
                      float* __restrict__ pm) {
    __shared__ unsigned short Xs[2][TILE_USH];     // 64 KB
    __shared__ float x2buf[2][16*68 + 8];          // padded, ~8.8 KB

    const int tid  = threadIdx.x;
    const int wv   = tid >> 6;    // 0..7
    const int lane = tid & 63;
    const int g    = lane >> 4;   // 0..3
    const int lr   = lane & 15;   // 0..15

    const int b   = blockIdx.x >> 1;
    const int whh = blockIdx.x & 1;

    const float* xb = xs + (size_t)b * (D_K * WH) + whh * WHH;

    // A fragments: -2*proto bf16, 64 rows x full K per wave
    bf16x8 af[4][8];
#pragma unroll
    for (int mf = 0; mf < 4; ++mf) {
        const unsigned short* rp = pb + (size_t)(64*wv + 16*mf + lr) * D_K + 8*g;
#pragma unroll
        for (int ks = 0; ks < 8; ++ks)
            af[mf][ks] = *reinterpret_cast<const bf16x8*>(rp + 32*ks);
    }

    const int n4 = tid & 7;    // col-quad within a 32-col half
    const int kq = tid >> 3;   // 0..63  (k-quad; 512 threads cover all 256 k)

    float rmin[4][4];
#pragma unroll
    for (int mf = 0; mf < 4; ++mf)
#pragma unroll
        for (int r = 0; r < 4; ++r) rmin[mf][r] = 3.0e38f;

    f32x4 ld[4];   // 16 floats: 4 k-rows x 4 cols (ONE set, R7 budget)

#define LOAD_H(T, H) do {                                                     \
        int colb = (T) * NT + 32*(H) + 4 * n4;                                \
        if (colb > WHH - 4) colb = WHH - 4;                                   \
        const float* rowp = xb + (size_t)(4*kq) * WH + colb;                  \
        _Pragma("unroll")                                                     \
        for (int r = 0; r < 4; ++r)                                           \
            ld[r] = *reinterpret_cast<const f32x4*>(rowp + r * WH);           \
    } while (0)

// element (n,k): granule kg=k>>3 stored at slot kg ^ ((n ^ (n>>2)) & 7)
#define STAGE_H(H, DST) do {                                                  \
        f32x4 x2a = {0.f, 0.f, 0.f, 0.f};                                     \
        _Pragma("unroll")                                                     \
        for (int r = 0; r < 4; ++r) {                                         \
            f32x4 v = ld[r];                                                  \
            x2a[0] += v[0]*v[0]; x2a[1] += v[1]*v[1];                         \
            x2a[2] += v[2]*v[2]; x2a[3] += v[3]*v[3];                         \
        }                                                                     \
        _Pragma("unroll")                                                     \
        for (int c = 0; c < 4; ++c) {                                         \
            int n = 32*(H) + 4*n4 + c;                                        \
            int key = (n ^ (n >> 2)) & 7;                                     \
            float2 f01 = make_float2(ld[0][c], ld[1][c]);                     \
            float2 f23 = make_float2(ld[2][c], ld[3][c]);                     \
            __hip_bfloat162 b01 = __float22bfloat162_rn(f01);                 \
            __hip_bfloat162 b23 = __float22bfloat162_rn(f23);                 \
            uint2 w;                                                          \
            w.x = *reinterpret_cast<unsigned int*>(&b01);                     \
            w.y = *reinterpret_cast<unsigned int*>(&b23);                     \
            int off = n*256 + (((kq >> 1) ^ key) << 3) + ((kq & 1) << 2);     \
            *reinterpret_cast<uint2*>(&Xs[DST][off]) = w;                     \
        }                                                                     \
        _Pragma("unroll")                                                     \
        for (int c = 0; c < 4; ++c) {                                         \
            x2a[c] += __shfl_xor(x2a[c], 8, 64);                              \
            x2a[c] += __shfl_xor(x2a[c], 16, 64);                             \
            x2a[c] += __shfl_xor(x2a[c], 32, 64);                             \
        }                                                                     \
        if (lane < 8) {                                                       \
            _Pragma("unroll")                                                 \
            for (int c = 0; c < 4; ++c)                                       \
                x2buf[DST][(8*(H) + lane)*68 + c*8 + wv] = x2a[c];            \
        }                                                                     \
    } while (0)

// x2 for this lane's column (n = 16*NF + lr): 8 wave-partials, 2 b128
#define X2_READ(BUF, NF, OUT) do {                                            \
        int n = 16*(NF) + lr;                                                 \
        const float* xp = &x2buf[BUF][(n >> 2)*68 + (n & 3)*8];               \
        f32x4 q0 = *reinterpret_cast<const f32x4*>(xp);                       \
        f32x4 q1 = *reinterpret_cast<const f32x4*>(xp + 4);                   \
        OUT = ((q0[0]+q0[1]) + (q0[2]+q0[3]))                                 \
            + ((q1[0]+q1[1]) + (q1[2]+q1[3]));                                \
    } while (0)

// one nf-burst: 8 ks x 4 mf MFMAs on column group NF into ACC[4]
#define BURST(BUF, NF, ACC) do {                                              \
        __builtin_amdgcn_s_setprio(1);                                        \
        _Pragma("unroll")                                                     \
        for (int ks = 0; ks < 8; ++ks) {                                      \
            int n = 16*(NF) + lr;                                             \
            int key = (n ^ (n >> 2)) & 7;                                     \
            int off = n*256 + (((((ks) << 2) + g) ^ key) << 3);               \
            bf16x8 bfr = *reinterpret_cast<const bf16x8*>(&Xs[BUF][off]);     \
            _Pragma("unroll")                                                 \
            for (int mf = 0; mf < 4; ++mf)                                    \
                ACC[mf] = __builtin_amdgcn_mfma_f32_16x16x32_bf16(            \
                    af[mf][ks], bfr, ACC[mf], 0, 0, 0);                       \
        }                                                                     \
        __builtin_amdgcn_s_setprio(0);                                        \
    } while (0)

#define NF_STEP(BUF, NF) do {                                                 \
        f32x4 acc[4];                                                         \
        float x2v; X2_READ(BUF, NF, x2v);                                     \
        _Pragma("unroll")                                                     \
        for (int mf = 0; mf < 4; ++mf)                                        \
            acc[mf] = (f32x4){x2v, x2v, x2v, x2v};                            \
        BURST(BUF, NF, acc);                                                  \
        _Pragma("unroll")                                                     \
        for (int mf = 0; mf < 4; ++mf)                                        \
            _Pragma("unroll")                                                 \
            for (int r = 0; r < 4; ++r)                                       \
                rmin[mf][r] = fminf(rmin[mf][r], acc[mf][r]);                 \
    } while (0)

    // prologue: stage tile 0 (both halves) into buffer 0
    LOAD_H(0, 0); STAGE_H(0, 0);
    LOAD_H(0, 1); STAGE_H(1, 0);
    __syncthreads();

    int buf = 0;
    for (int t = 0; t < NTILES; ++t) {
        const bool more = (t + 1 < NTILES);

        if (more) LOAD_H(t + 1, 0);     // issue half-0 loads for t+1

        NF_STEP(buf, 0);                // 32 MFMA (cols 0-15)
        NF_STEP(buf, 1);                // 32 MFMA (cols 16-31)

        if (more) {
            STAGE_H(0, buf ^ 1);        // stage half-0 (drain covered above)
            LOAD_H(t + 1, 1);           // issue half-1 loads
        }

        NF_STEP(buf, 2);                // 32 MFMA (cols 32-47)
        NF_STEP(buf, 3);                // 32 MFMA (cols 48-63)

        if (more) {
            STAGE_H(1, buf ^ 1);        // stage half-1
            __syncthreads();            // ONE barrier per 64-col tile
        }
        buf ^= 1;
    }

    // min across the 16 column-lanes (flips only lr bits; g preserved)
#pragma unroll
    for (int mf = 0; mf < 4; ++mf)
#pragma unroll
        for (int r = 0; r < 4; ++r) {
            float v = rmin[mf][r];
#pragma unroll
            for (int m = 1; m <= 8; m <<= 1)
                v = fminf(v, __shfl_xor(v, m, 64));
            rmin[mf][r] = v;
        }

    if (lr == 0) {
        float* pmw = pm + ((size_t)b * 2 + whh) * P_PAD;
#pragma unroll
        for (int mf = 0; mf < 4; ++mf)
#pragma unroll
            for (int r = 0; r < 4; ++r)
                pmw[64*wv + 16*mf + 4*g + r] = rmin[mf][r];
    }
#undef LOAD_H
#undef STAGE_H
#undef X2_READ
#undef BURST
#undef NF_STEP
}

// --- combine halves + exp(-sqrt) + tree path products + pa @ ds -----------
__global__ __launch_bounds__(256)
void out_kernel(const float* __restrict__ pm, const float* __restrict__ p2,
                const float* __restrict__ ds, float* __restrict__ out) {
    __shared__ float sim[NLEAF];
    __shared__ float pa[NLEAF];
    int b = blockIdx.x;
    int t = threadIdx.x;
    const float* pm0 = pm + (size_t)b * 2 * P_PAD;
#pragma unroll
    for (int j = 0; j < 2; ++j) {
        int p = t + 256 * j;
        float m = fminf(pm0[p], pm0[P_PAD + p]);
        float sq = m + p2[p];
        sim[p] = expf(-sqrtf(fabsf(sq) + 1e-14f));
    }
    __syncthreads();
#pragma unroll
    for (int j = 0; j < 2; ++j) {
        int leaf = t + 256 * j;
        int node = 0;
        float prod = 1.f;
#pragma unroll
        for (int st = 0; st < TDEPTH; ++st) {
            int bit = (leaf >> (TDEPTH - 1 - st)) & 1;
            float sv = sim[node];
            prod *= bit ? sv : (1.f - sv);
            node = 2 * node + 1 + bit;
        }
        pa[leaf] = prod;
    }
    __syncthreads();
    if (t < C_OUT) {
        float a0 = 0.f, a1 = 0.f, a2 = 0.f, a3 = 0.f;
        for (int l = 0; l < NLEAF; l += 4) {
            a0 += pa[l + 0] * ds[(size_t)(l + 0) * C_OUT + t];
            a1 += pa[l + 1] * ds[(size_t)(l + 1) * C_OUT + t];
            a2 += pa[l + 2] * ds[(size_t)(l + 2) * C_OUT + t];
            a3 += pa[l + 3] * ds[(size_t)(l + 3) * C_OUT + t];
        }
        out[(size_t)b * C_OUT + t] = (a0 + a1) + (a2 + a3);
    }
}

extern "C" void kernel_launch(void* const* d_in, const int* in_sizes, int n_in,
                              void* d_out, int out_size, void* d_ws, size_t ws_size,
                              hipStream_t stream) {
    (void)in_sizes; (void)n_in; (void)out_size; (void)ws_size;
    const float* xs     = (const float*)d_in[0];
    const float* protos = (const float*)d_in[1];
    const float* lp     = (const float*)d_in[2];
    float* out = (float*)d_out;

    char* ws = (char*)d_ws;
    unsigned short* pb = (unsigned short*)(ws + WS_PB);
    float* p2   = (float*)(ws + WS_P2);
    float* dsm  = (float*)(ws + WS_DS);
    float* pm   = (float*)(ws + WS_PM);

    prep2_kernel<<<1024, 64, 0, stream>>>(protos, lp, pb, p2, dsm);
    proto_min_kernel<<<256, 512, 0, stream>>>(xs, pb, pm);
    out_kernel<<<128, 256, 0, stream>>>(pm, p2, dsm, out);
}

// Round 12
// 58.053 us; speedup vs baseline: 2.1652x; 2.1652x over previous
//
#include <hip/hip_runtime.h>
#include <hip/hip_bf16.h>

typedef __attribute__((ext_vector_type(8))) short bf16x8;
typedef __attribute__((ext_vector_type(4))) float f32x4;

#define D_K    256
#define WH     784
#define WHH    392
#define P_REAL 511
#define P_PAD  512
#define C_OUT  200
#define NLEAF  512
#define TDEPTH 9

#define NT      32
#define NTILES  13          // 13*32 >= 392 (tail clamped to duplicate columns)
#define TILE_USH 8192       // 32 n x 256 k ushorts = 16 KB

// workspace offsets (bytes)
#define WS_PB   0                          // 512*256*2   = 262144
#define WS_P2   262144                     // 512*4
#define WS_DS   264192                     // 512*200*4
#define WS_PM   673792                     // 128*2*512*4
// total 1198080

static __device__ __forceinline__ unsigned short f2bf(float x) {
    union { float f; unsigned int u; } v; v.f = x;
    unsigned int r = v.u + 0x7FFFu + ((v.u >> 16) & 1u);   // RNE
    return (unsigned short)(r >> 16);
}

// --- fused prep (proto -> bf16(-2p) + p2) and softmax(leaf_params) --------
__global__ __launch_bounds__(64)
void prep2_kernel(const float* __restrict__ protos, const float* __restrict__ lp,
                  unsigned short* __restrict__ pb, float* __restrict__ p2,
                  float* __restrict__ ds) {
    int bid = blockIdx.x;
    int l = threadIdx.x;
    if (bid < P_PAD) {
        int p = bid;
        f32x4 v = {0.f, 0.f, 0.f, 0.f};
        if (p < P_REAL)
            v = *reinterpret_cast<const f32x4*>(protos + (size_t)p * D_K + 4 * l);
        ushort4 w;
        w.x = f2bf(-2.f * v[0]); w.y = f2bf(-2.f * v[1]);
        w.z = f2bf(-2.f * v[2]); w.w = f2bf(-2.f * v[3]);
        *reinterpret_cast<ushort4*>(pb + (size_t)p * D_K + 4 * l) = w;
        float s = v[0]*v[0] + v[1]*v[1] + v[2]*v[2] + v[3]*v[3];
#pragma unroll
        for (int m = 32; m >= 1; m >>= 1) s += __shfl_xor(s, m, 64);
        if (l == 0) p2[p] = s;
    } else {
        int row = bid - P_PAD;
        float v[4];
        float mx = -3.4e38f;
#pragma unroll
        for (int i = 0; i < 4; ++i) {
            int c = l + 64 * i;
            v[i] = (c < C_OUT) ? lp[(size_t)row * C_OUT + c] : -3.4e38f;
            mx = fmaxf(mx, v[i]);
        }
#pragma unroll
        for (int m = 32; m >= 1; m >>= 1) mx = fmaxf(mx, __shfl_xor(mx, m, 64));
        float sum = 0.f;
#pragma unroll
        for (int i = 0; i < 4; ++i) {
            int c = l + 64 * i;
            if (c < C_OUT) { v[i] = expf(v[i] - mx); sum += v[i]; }
        }
#pragma unroll
        for (int m = 32; m >= 1; m >>= 1) sum += __shfl_xor(sum, m, 64);
        float inv = 1.f / sum;
#pragma unroll
        for (int i = 0; i < 4; ++i) {
            int c = l + 64 * i;
            if (c < C_OUT) ds[(size_t)row * C_OUT + c] = v[i] * inv;
        }
    }
}

// --- main: read-once fused distance+min (R7 structure, improved XOR key) --
// grid 256 = 128 b x 2 wh-halves, 512 threads (8 waves), 1 block/CU.
// Each wave holds 64 p-rows (af[4][8]); 8 waves = all 512 protos -> each
// block streams its xs half exactly once. Double-buffered, ONE barrier per
// tile. Granule key (n ^ (n>>2)) & 7 on BOTH stage-write and fragment-read
// (same involution): conflict-free staging writes, 2-way (free) reads.
__global__ __launch_bounds__(512, 2)
void proto_min_kernel(const float* __restrict__ xs,
                      const unsigned short* __restrict__ pb,
                      float* __restrict__ pm) {
    __shared__ unsigned short Xs[2][TILE_USH];     // 32 KB
    __shared__ float x2buf[2][8*68 + 8];           // bank-padded

    const int tid  = threadIdx.x;
    const int wv   = tid >> 6;    // 0..7
    const int lane = tid & 63;
    const int g    = lane >> 4;   // 0..3
    const int lr   = lane & 15;   // 0..15

    const int b   = blockIdx.x >> 1;
    const int whh = blockIdx.x & 1;

    const float* xb = xs + (size_t)b * (D_K * WH) + whh * WHH;

    // A fragments: -2*proto bf16, 64 rows x full K per wave
    bf16x8 af[4][8];
#pragma unroll
    for (int mf = 0; mf < 4; ++mf) {
        const unsigned short* rp = pb + (size_t)(64*wv + 16*mf + lr) * D_K + 8*g;
#pragma unroll
        for (int ks = 0; ks < 8; ++ks)
            af[mf][ks] = *reinterpret_cast<const bf16x8*>(rp + 32*ks);
    }

    const int n4 = tid & 7;    // col-quad within tile (8 quads x 4 cols)
    const int kq = tid >> 3;   // 0..63  (k-quad; 512 threads cover all 256 k)

    float rmin[4][4];
#pragma unroll
    for (int mf = 0; mf < 4; ++mf)
#pragma unroll
        for (int r = 0; r < 4; ++r) rmin[mf][r] = 3.0e38f;

    f32x4 ld[4];   // 16 floats: 4 k-rows x 4 cols

#define LOAD_TILE(T) do {                                                     \
        int colb = (T) * NT + 4 * n4;                                         \
        if (colb > WHH - 4) colb = WHH - 4;                                   \
        const float* rowp = xb + (size_t)(4*kq) * WH + colb;                  \
        _Pragma("unroll")                                                     \
        for (int r = 0; r < 4; ++r)                                           \
            ld[r] = *reinterpret_cast<const f32x4*>(rowp + r * WH);           \
    } while (0)

// element (n,k): granule kg=k>>3 stored at slot kg ^ ((n ^ (n>>2)) & 7)
#define STAGE_TILE(DST) do {                                                  \
        f32x4 x2a = {0.f, 0.f, 0.f, 0.f};                                     \
        _Pragma("unroll")                                                     \
        for (int r = 0; r < 4; ++r) {                                         \
            f32x4 v = ld[r];                                                  \
            x2a[0] += v[0]*v[0]; x2a[1] += v[1]*v[1];                         \
            x2a[2] += v[2]*v[2]; x2a[3] += v[3]*v[3];                         \
        }                                                                     \
        _Pragma("unroll")                                                     \
        for (int c = 0; c < 4; ++c) {                                         \
            int n = 4*n4 + c;                                                 \
            int key = (n ^ (n >> 2)) & 7;                                     \
            float2 f01 = make_float2(ld[0][c], ld[1][c]);                     \
            float2 f23 = make_float2(ld[2][c], ld[3][c]);                     \
            __hip_bfloat162 b01 = __float22bfloat162_rn(f01);                 \
            __hip_bfloat162 b23 = __float22bfloat162_rn(f23);                 \
            uint2 w;                                                          \
            w.x = *reinterpret_cast<unsigned int*>(&b01);                     \
            w.y = *reinterpret_cast<unsigned int*>(&b23);                     \
            int off = n*256 + (((kq >> 1) ^ key) << 3) + ((kq & 1) << 2);     \
            *reinterpret_cast<uint2*>(&Xs[DST][off]) = w;                     \
        }                                                                     \
        _Pragma("unroll")                                                     \
        for (int c = 0; c < 4; ++c) {                                         \
            x2a[c] += __shfl_xor(x2a[c], 8, 64);                              \
            x2a[c] += __shfl_xor(x2a[c], 16, 64);                             \
            x2a[c] += __shfl_xor(x2a[c], 32, 64);                             \
        }                                                                     \
        if (lane < 8) {                                                       \
            _Pragma("unroll")                                                 \
            for (int c = 0; c < 4; ++c)                                       \
                x2buf[DST][lane*68 + c*8 + wv] = x2a[c];                      \
        }                                                                     \
    } while (0)

    // prologue
    LOAD_TILE(0);
    STAGE_TILE(0);
    __syncthreads();

    int buf = 0;
    for (int t = 0; t < NTILES; ++t) {
        const bool more = (t + 1 < NTILES);

        // issue next tile's loads first; latency hides under the MFMA phase
        if (more) LOAD_TILE(t + 1);

        // x2 for this lane's 2 columns: 8 wave-partials = 2 x b128 + adds
        float x2v[2];
#pragma unroll
        for (int nf = 0; nf < 2; ++nf) {
            int n = 16*nf + lr;
            const float* xp = &x2buf[buf][(n >> 2)*68 + (n & 3)*8];
            f32x4 q0 = *reinterpret_cast<const f32x4*>(xp);
            f32x4 q1 = *reinterpret_cast<const f32x4*>(xp + 4);
            x2v[nf] = ((q0[0]+q0[1]) + (q0[2]+q0[3]))
                    + ((q1[0]+q1[1]) + (q1[2]+q1[3]));
        }

        f32x4 acc[4][2];
#pragma unroll
        for (int mf = 0; mf < 4; ++mf) {
            acc[mf][0] = (f32x4){x2v[0], x2v[0], x2v[0], x2v[0]};
            acc[mf][1] = (f32x4){x2v[1], x2v[1], x2v[1], x2v[1]};
        }

        __builtin_amdgcn_s_setprio(1);
#pragma unroll
        for (int ks = 0; ks < 8; ++ks) {
            bf16x8 bfr[2];
#pragma unroll
            for (int nf = 0; nf < 2; ++nf) {
                int n = 16*nf + lr;
                int key = (n ^ (n >> 2)) & 7;
                int off = n*256 + ((((ks << 2) + g) ^ key) << 3);
                bfr[nf] = *reinterpret_cast<const bf16x8*>(&Xs[buf][off]);
            }
#pragma unroll
            for (int mf = 0; mf < 4; ++mf)
#pragma unroll
                for (int nf = 0; nf < 2; ++nf)
                    acc[mf][nf] = __builtin_amdgcn_mfma_f32_16x16x32_bf16(
                        af[mf][ks], bfr[nf], acc[mf][nf], 0, 0, 0);
        }
        __builtin_amdgcn_s_setprio(0);

        // stage next tile into the other buffer (other waves keep MFMAing)
        if (more) STAGE_TILE(buf ^ 1);

        // running min over this tile's columns
#pragma unroll
        for (int mf = 0; mf < 4; ++mf)
#pragma unroll
            for (int r = 0; r < 4; ++r)
                rmin[mf][r] = fminf(rmin[mf][r],
                                    fminf(acc[mf][0][r], acc[mf][1][r]));

        __syncthreads();
        buf ^= 1;
    }

    // min across the 16 column-lanes (flips only lr bits; g preserved)
#pragma unroll
    for (int mf = 0; mf < 4; ++mf)
#pragma unroll
        for (int r = 0; r < 4; ++r) {
            float v = rmin[mf][r];
#pragma unroll
            for (int m = 1; m <= 8; m <<= 1)
                v = fminf(v, __shfl_xor(v, m, 64));
            rmin[mf][r] = v;
        }

    if (lr == 0) {
        float* pmw = pm + ((size_t)b * 2 + whh) * P_PAD;
#pragma unroll
        for (int mf = 0; mf < 4; ++mf)
#pragma unroll
            for (int r = 0; r < 4; ++r)
                pmw[64*wv + 16*mf + 4*g + r] = rmin[mf][r];
    }
#undef LOAD_TILE
#undef STAGE_TILE
}

// --- combine halves + exp(-sqrt) + tree path products + pa @ ds -----------
__global__ __launch_bounds__(256)
void out_kernel(const float* __restrict__ pm, const float* __restrict__ p2,
                const float* __restrict__ ds, float* __restrict__ out) {
    __shared__ float sim[NLEAF];
    __shared__ float pa[NLEAF];
    int b = blockIdx.x;
    int t = threadIdx.x;
    const float* pm0 = pm + (size_t)b * 2 * P_PAD;
#pragma unroll
    for (int j = 0; j < 2; ++j) {
        int p = t + 256 * j;
        float m = fminf(pm0[p], pm0[P_PAD + p]);
        float sq = m + p2[p];
        sim[p] = expf(-sqrtf(fabsf(sq) + 1e-14f));
    }
    __syncthreads();
#pragma unroll
    for (int j = 0; j < 2; ++j) {
        int leaf = t + 256 * j;
        int node = 0;
        float prod = 1.f;
#pragma unroll
        for (int st = 0; st < TDEPTH; ++st) {
            int bit = (leaf >> (TDEPTH - 1 - st)) & 1;
            float sv = sim[node];
            prod *= bit ? sv : (1.f - sv);
            node = 2 * node + 1 + bit;
        }
        pa[leaf] = prod;
    }
    __syncthreads();
    if (t < C_OUT) {
        float a0 = 0.f, a1 = 0.f, a2 = 0.f, a3 = 0.f;
        for (int l = 0; l < NLEAF; l += 4) {
            a0 += pa[l + 0] * ds[(size_t)(l + 0) * C_OUT + t];
            a1 += pa[l + 1] * ds[(size_t)(l + 1) * C_OUT + t];
            a2 += pa[l + 2] * ds[(size_t)(l + 2) * C_OUT + t];
            a3 += pa[l + 3] * ds[(size_t)(l + 3) * C_OUT + t];
        }
        out[(size_t)b * C_OUT + t] = (a0 + a1) + (a2 + a3);
    }
}

extern "C" void kernel_launch(void* const* d_in, const int* in_sizes, int n_in,
                              void* d_out, int out_size, void* d_ws, size_t ws_size,
                              hipStream_t stream) {
    (void)in_sizes; (void)n_in; (void)out_size; (void)ws_size;
    const float* xs     = (const float*)d_in[0];
    const float* protos = (const float*)d_in[1];
    const float* lp     = (const float*)d_in[2];
    float* out = (float*)d_out;

    char* ws = (char*)d_ws;
    unsigned short* pb = (unsigned short*)(ws + WS_PB);
    float* p2   = (float*)(ws + WS_P2);
    float* dsm  = (float*)(ws + WS_DS);
    float* pm   = (float*)(ws + WS_PM);

    prep2_kernel<<<1024, 64, 0, stream>>>(protos, lp, pb, p2, dsm);
    proto_min_kernel<<<256, 512, 0, stream>>>(xs, pb, pm);
    out_kernel<<<128, 256, 0, stream>>>(pm, p2, dsm, out);
}

// Round 13
// 52.389 us; speedup vs baseline: 2.3993x; 1.1081x over previous
//
#include <hip/hip_runtime.h>
#include <hip/hip_bf16.h>

typedef __attribute__((ext_vector_type(8))) int   i32x8;
typedef __attribute__((ext_vector_type(4))) int   i32x4;
typedef __attribute__((ext_vector_type(4))) float f32x4;

#define D_K    256
#define WH     784
#define WHH    392
#define P_REAL 511
#define P_PAD  512
#define C_OUT  200
#define NLEAF  512
#define TDEPTH 9

#define NT      32
#define NTILES  13          // 13*32 >= 392 (tail clamped to duplicate columns)
#define TILE_B  8192        // 32 n x 256 k fp8 bytes

// workspace offsets (bytes)
#define WS_PB8  0                          // 512*256     = 131072
#define WS_P2   131072                     // 512*4
#define WS_DS   133120                     // 512*200*4
#define WS_PM   542720                     // 128*2*512*4
// total 1067008

#define SCALE_ONE 0x7F7F7F7F               // E8M0 = 127 -> 2^0 in every byte

// --- fused prep (proto -> fp8(-2p) + p2) and softmax(leaf_params) ---------
__global__ __launch_bounds__(64)
void prep2_kernel(const float* __restrict__ protos, const float* __restrict__ lp,
                  unsigned char* __restrict__ pb8, float* __restrict__ p2,
                  float* __restrict__ ds) {
    int bid = blockIdx.x;
    int l = threadIdx.x;
    if (bid < P_PAD) {
        int p = bid;
        f32x4 v = {0.f, 0.f, 0.f, 0.f};
        if (p < P_REAL)
            v = *reinterpret_cast<const f32x4*>(protos + (size_t)p * D_K + 4 * l);
        int u = 0;
        u = __builtin_amdgcn_cvt_pk_fp8_f32(-2.f * v[0], -2.f * v[1], u, false);
        u = __builtin_amdgcn_cvt_pk_fp8_f32(-2.f * v[2], -2.f * v[3], u, true);
        *reinterpret_cast<int*>(pb8 + (size_t)p * D_K + 4 * l) = u;
        float s = v[0]*v[0] + v[1]*v[1] + v[2]*v[2] + v[3]*v[3];
#pragma unroll
        for (int m = 32; m >= 1; m >>= 1) s += __shfl_xor(s, m, 64);
        if (l == 0) p2[p] = s;
    } else {
        int row = bid - P_PAD;
        float v[4];
        float mx = -3.4e38f;
#pragma unroll
        for (int i = 0; i < 4; ++i) {
            int c = l + 64 * i;
            v[i] = (c < C_OUT) ? lp[(size_t)row * C_OUT + c] : -3.4e38f;
            mx = fmaxf(mx, v[i]);
        }
#pragma unroll
        for (int m = 32; m >= 1; m >>= 1) mx = fmaxf(mx, __shfl_xor(mx, m, 64));
        float sum = 0.f;
#pragma unroll
        for (int i = 0; i < 4; ++i) {
            int c = l + 64 * i;
            if (c < C_OUT) { v[i] = expf(v[i] - mx); sum += v[i]; }
        }
#pragma unroll
        for (int m = 32; m >= 1; m >>= 1) sum += __shfl_xor(sum, m, 64);
        float inv = 1.f / sum;
#pragma unroll
        for (int i = 0; i < 4; ++i) {
            int c = l + 64 * i;
            if (c < C_OUT) ds[(size_t)row * C_OUT + c] = v[i] * inv;
        }
    }
}

// --- main: read-once fused distance+min, MX-fp8 K=128 MFMA ----------------
// grid 256 = 128 b x 2 wh-halves, 512 threads (8 waves), 1 block/CU.
// Each wave holds 64 p-rows as fp8 A-frags af[4][2] (i32x8, 64 VGPRs —
// HALF the bf16 footprint); 8 waves = all 512 protos -> xs read once.
// mfma_scale_f32_16x16x128_f8f6f4 with unit scales: 2x bf16 rate, half
// LDS traffic. x2/p2 stay fp32 (only the cross-term is quantized).
// Granule-16 XOR key (n ^ (n>>2)) & 7 on both stage-write & B-read sides.
__global__ __launch_bounds__(512, 2)
void proto_min_kernel(const float* __restrict__ xs,
                      const unsigned char* __restrict__ pb8,
                      float* __restrict__ pm) {
    __shared__ unsigned char Xs[2][TILE_B];        // 16 KB
    __shared__ float x2buf[2][8*68 + 8];           // bank-padded

    const int tid  = threadIdx.x;
    const int wv   = tid >> 6;    // 0..7
    const int lane = tid & 63;
    const int lh   = lane >> 4;   // 0..3 (k-group for A/B frags)
    const int lr   = lane & 15;   // 0..15 (row of A / col of B)

    const int b   = blockIdx.x >> 1;
    const int whh = blockIdx.x & 1;

    const float* xb = xs + (size_t)b * (D_K * WH) + whh * WHH;

    // A fragments: fp8(-2p), row = 64wv + 16mf + lr, k = ks*128 + lh*32 + e
    i32x8 af[4][2];
#pragma unroll
    for (int mf = 0; mf < 4; ++mf) {
        const unsigned char* rp = pb8 + (size_t)(64*wv + 16*mf + lr) * D_K + lh*32;
        af[mf][0] = *reinterpret_cast<const i32x8*>(rp);
        af[mf][1] = *reinterpret_cast<const i32x8*>(rp + 128);
    }

    const int n4 = tid & 7;    // col-quad within tile (8 quads x 4 cols)
    const int kq = tid >> 3;   // 0..63  (k-quad; 512 threads cover all 256 k)

    f32x4 rmin[4];
#pragma unroll
    for (int mf = 0; mf < 4; ++mf)
        rmin[mf] = (f32x4){3.0e38f, 3.0e38f, 3.0e38f, 3.0e38f};

    f32x4 ld[4];   // 16 floats: 4 k-rows x 4 cols

#define LOAD_TILE(T) do {                                                     \
        int colb = (T) * NT + 4 * n4;                                         \
        if (colb > WHH - 4) colb = WHH - 4;                                   \
        const float* rowp = xb + (size_t)(4*kq) * WH + colb;                  \
        _Pragma("unroll")                                                     \
        for (int r = 0; r < 4; ++r)                                           \
            ld[r] = *reinterpret_cast<const f32x4*>(rowp + r * WH);           \
    } while (0)

// element (n,k): 16B granule kg=k>>4 stored at slot kg ^ ((n ^ (n>>2)) & 7)
#define STAGE_TILE(DST) do {                                                  \
        f32x4 x2a = {0.f, 0.f, 0.f, 0.f};                                     \
        _Pragma("unroll")                                                     \
        for (int r = 0; r < 4; ++r) {                                         \
            f32x4 v = ld[r];                                                  \
            x2a[0] += v[0]*v[0]; x2a[1] += v[1]*v[1];                         \
            x2a[2] += v[2]*v[2]; x2a[3] += v[3]*v[3];                         \
        }                                                                     \
        _Pragma("unroll")                                                     \
        for (int c = 0; c < 4; ++c) {                                         \
            int n = 4*n4 + c;                                                 \
            int key = (n ^ (n >> 2)) & 7;                                     \
            int u = 0;                                                        \
            u = __builtin_amdgcn_cvt_pk_fp8_f32(ld[0][c], ld[1][c], u, false);\
            u = __builtin_amdgcn_cvt_pk_fp8_f32(ld[2][c], ld[3][c], u, true); \
            int off = n*256 + (((kq >> 2) ^ key) << 4) + ((kq & 3) << 2);     \
            *reinterpret_cast<int*>(&Xs[DST][off]) = u;                       \
        }                                                                     \
        _Pragma("unroll")                                                     \
        for (int c = 0; c < 4; ++c) {                                         \
            x2a[c] += __shfl_xor(x2a[c], 8, 64);                              \
            x2a[c] += __shfl_xor(x2a[c], 16, 64);                             \
            x2a[c] += __shfl_xor(x2a[c], 32, 64);                             \
        }                                                                     \
        if (lane < 8) {                                                       \
            _Pragma("unroll")                                                 \
            for (int c = 0; c < 4; ++c)                                       \
                x2buf[DST][lane*68 + c*8 + wv] = x2a[c];                      \
        }                                                                     \
    } while (0)

    // prologue
    LOAD_TILE(0);
    STAGE_TILE(0);
    __syncthreads();

    int buf = 0;
    for (int t = 0; t < NTILES; ++t) {
        const bool more = (t + 1 < NTILES);

        // issue next tile's loads first; latency hides under the MFMA phase
        if (more) LOAD_TILE(t + 1);

        // x2 for this lane's 2 columns: 8 wave-partials = 2 x b128 + adds
        float x2v[2];
#pragma unroll
        for (int nf = 0; nf < 2; ++nf) {
            int n = 16*nf + lr;
            const float* xp = &x2buf[buf][(n >> 2)*68 + (n & 3)*8];
            f32x4 q0 = *reinterpret_cast<const f32x4*>(xp);
            f32x4 q1 = *reinterpret_cast<const f32x4*>(xp + 4);
            x2v[nf] = ((q0[0]+q0[1]) + (q0[2]+q0[3]))
                    + ((q1[0]+q1[1]) + (q1[2]+q1[3]));
        }

        // C init = x2 (C col = lane&15, same for all 4 regs of a fragment)
        f32x4 acc[4][2];
#pragma unroll
        for (int mf = 0; mf < 4; ++mf) {
            acc[mf][0] = (f32x4){x2v[0], x2v[0], x2v[0], x2v[0]};
            acc[mf][1] = (f32x4){x2v[1], x2v[1], x2v[1], x2v[1]};
        }

        __builtin_amdgcn_s_setprio(1);
#pragma unroll
        for (int ks = 0; ks < 2; ++ks) {
            i32x8 bfr[2];
#pragma unroll
            for (int nf = 0; nf < 2; ++nf) {
                int n = 16*nf + lr;
                int key = (n ^ (n >> 2)) & 7;
                int kg0 = ks*8 + lh*2;
                i32x4 lo = *reinterpret_cast<const i32x4*>(
                               &Xs[buf][n*256 + ((kg0 ^ key) << 4)]);
                i32x4 hi = *reinterpret_cast<const i32x4*>(
                               &Xs[buf][n*256 + (((kg0 + 1) ^ key) << 4)]);
                bfr[nf] = __builtin_shufflevector(lo, hi, 0,1,2,3,4,5,6,7);
            }
#pragma unroll
            for (int mf = 0; mf < 4; ++mf)
#pragma unroll
                for (int nf = 0; nf < 2; ++nf)
                    acc[mf][nf] = __builtin_amdgcn_mfma_scale_f32_16x16x128_f8f6f4(
                        af[mf][ks], bfr[nf], acc[mf][nf],
                        0, 0,                    // cbsz=FP8(A), blgp=FP8(B)
                        0, SCALE_ONE,            // scale A opsel, value (1.0)
                        0, SCALE_ONE);           // scale B opsel, value (1.0)
        }
        __builtin_amdgcn_s_setprio(0);

        // stage next tile into the other buffer (other waves keep MFMAing)
        if (more) STAGE_TILE(buf ^ 1);

        // running min over this tile's columns
#pragma unroll
        for (int mf = 0; mf < 4; ++mf)
#pragma unroll
            for (int r = 0; r < 4; ++r)
                rmin[mf][r] = fminf(rmin[mf][r],
                                    fminf(acc[mf][0][r], acc[mf][1][r]));

        __syncthreads();
        buf ^= 1;
    }

    // min across the 16 column-lanes (flips only lr bits; lh preserved)
#pragma unroll
    for (int mf = 0; mf < 4; ++mf)
#pragma unroll
        for (int r = 0; r < 4; ++r) {
            float v = rmin[mf][r];
#pragma unroll
            for (int m = 1; m <= 8; m <<= 1)
                v = fminf(v, __shfl_xor(v, m, 64));
            rmin[mf][r] = v;
        }

    if (lr == 0) {
        float* pmw = pm + ((size_t)b * 2 + whh) * P_PAD;
#pragma unroll
        for (int mf = 0; mf < 4; ++mf)
#pragma unroll
            for (int r = 0; r < 4; ++r)
                pmw[64*wv + 16*mf + 4*lh + r] = rmin[mf][r];
    }
#undef LOAD_TILE
#undef STAGE_TILE
}

// --- combine halves + exp(-sqrt) + tree path products + pa @ ds -----------
__global__ __launch_bounds__(256)
void out_kernel(const float* __restrict__ pm, const float* __restrict__ p2,
                const float* __restrict__ ds, float* __restrict__ out) {
    __shared__ float sim[NLEAF];
    __shared__ float pa[NLEAF];
    int b = blockIdx.x;
    int t = threadIdx.x;
    const float* pm0 = pm + (size_t)b * 2 * P_PAD;
#pragma unroll
    for (int j = 0; j < 2; ++j) {
        int p = t + 256 * j;
        float m = fminf(pm0[p], pm0[P_PAD + p]);
        float sq = m + p2[p];
        sim[p] = expf(-sqrtf(fabsf(sq) + 1e-14f));
    }
    __syncthreads();
#pragma unroll
    for (int j = 0; j < 2; ++j) {
        int leaf = t + 256 * j;
        int node = 0;
        float prod = 1.f;
#pragma unroll
        for (int st = 0; st < TDEPTH; ++st) {
            int bit = (leaf >> (TDEPTH - 1 - st)) & 1;
            float sv = sim[node];
            prod *= bit ? sv : (1.f - sv);
            node = 2 * node + 1 + bit;
        }
        pa[leaf] = prod;
    }
    __syncthreads();
    if (t < C_OUT) {
        float a0 = 0.f, a1 = 0.f, a2 = 0.f, a3 = 0.f;
        for (int l = 0; l < NLEAF; l += 4) {
            a0 += pa[l + 0] * ds[(size_t)(l + 0) * C_OUT + t];
            a1 += pa[l + 1] * ds[(size_t)(l + 1) * C_OUT + t];
            a2 += pa[l + 2] * ds[(size_t)(l + 2) * C_OUT + t];
            a3 += pa[l + 3] * ds[(size_t)(l + 3) * C_OUT + t];
        }
        out[(size_t)b * C_OUT + t] = (a0 + a1) + (a2 + a3);
    }
}

extern "C" void kernel_launch(void* const* d_in, const int* in_sizes, int n_in,
                              void* d_out, int out_size, void* d_ws, size_t ws_size,
                              hipStream_t stream) {
    (void)in_sizes; (void)n_in; (void)out_size; (void)ws_size;
    const float* xs     = (const float*)d_in[0];
    const float* protos = (const float*)d_in[1];
    const float* lp     = (const float*)d_in[2];
    float* out = (float*)d_out;

    char* ws = (char*)d_ws;
    unsigned char* pb8 = (unsigned char*)(ws + WS_PB8);
    float* p2   = (float*)(ws + WS_P2);
    float* dsm  = (float*)(ws + WS_DS);
    float* pm   = (float*)(ws + WS_PM);

    prep2_kernel<<<1024, 64, 0, stream>>>(protos, lp, pb8, p2, dsm);
    proto_min_kernel<<<256, 512, 0, stream>>>(xs, pb8, pm);
    out_kernel<<<128, 256, 0, stream>>>(pm, p2, dsm, out);
}

// Round 14
// 49.791 us; speedup vs baseline: 2.5244x; 1.0522x over previous
//
#include <hip/hip_runtime.h>
#include <hip/hip_bf16.h>

typedef __attribute__((ext_vector_type(8))) int   i32x8;
typedef __attribute__((ext_vector_type(4))) int   i32x4;
typedef __attribute__((ext_vector_type(4))) float f32x4;

#define D_K    256
#define WH     784
#define WHH    392
#define P_REAL 511
#define P_PAD  512
#define C_OUT  200
#define NLEAF  512
#define TDEPTH 9

#define NT      32
#define NTILES  13          // 13*32 >= 392 (tail clamped to duplicate columns)
#define TILE_B  8192        // 32 n x 256 k fp8 bytes

// workspace offsets (bytes)
#define WS_PB8  0                          // 512*256     = 131072
#define WS_P2   131072                     // 512*4
#define WS_DS   133120                     // 512*200*4
#define WS_PM   542720                     // 128*2*512*4
// total 1067008

#define SCALE_ONE 0x7F7F7F7F               // E8M0 = 127 -> 2^0 in every byte

// --- fused prep (proto -> fp8(-2p) + p2) and softmax(leaf_params) ---------
__global__ __launch_bounds__(64)
void prep2_kernel(const float* __restrict__ protos, const float* __restrict__ lp,
                  unsigned char* __restrict__ pb8, float* __restrict__ p2,
                  float* __restrict__ ds) {
    int bid = blockIdx.x;
    int l = threadIdx.x;
    if (bid < P_PAD) {
        int p = bid;
        f32x4 v = {0.f, 0.f, 0.f, 0.f};
        if (p < P_REAL)
            v = *reinterpret_cast<const f32x4*>(protos + (size_t)p * D_K + 4 * l);
        int u = 0;
        u = __builtin_amdgcn_cvt_pk_fp8_f32(-2.f * v[0], -2.f * v[1], u, false);
        u = __builtin_amdgcn_cvt_pk_fp8_f32(-2.f * v[2], -2.f * v[3], u, true);
        *reinterpret_cast<int*>(pb8 + (size_t)p * D_K + 4 * l) = u;
        float s = v[0]*v[0] + v[1]*v[1] + v[2]*v[2] + v[3]*v[3];
#pragma unroll
        for (int m = 32; m >= 1; m >>= 1) s += __shfl_xor(s, m, 64);
        if (l == 0) p2[p] = s;
    } else {
        int row = bid - P_PAD;
        float v[4];
        float mx = -3.4e38f;
#pragma unroll
        for (int i = 0; i < 4; ++i) {
            int c = l + 64 * i;
            v[i] = (c < C_OUT) ? lp[(size_t)row * C_OUT + c] : -3.4e38f;
            mx = fmaxf(mx, v[i]);
        }
#pragma unroll
        for (int m = 32; m >= 1; m >>= 1) mx = fmaxf(mx, __shfl_xor(mx, m, 64));
        float sum = 0.f;
#pragma unroll
        for (int i = 0; i < 4; ++i) {
            int c = l + 64 * i;
            if (c < C_OUT) { v[i] = expf(v[i] - mx); sum += v[i]; }
        }
#pragma unroll
        for (int m = 32; m >= 1; m >>= 1) sum += __shfl_xor(sum, m, 64);
        float inv = 1.f / sum;
#pragma unroll
        for (int i = 0; i < 4; ++i) {
            int c = l + 64 * i;
            if (c < C_OUT) ds[(size_t)row * C_OUT + c] = v[i] * inv;
        }
    }
}

// --- main: read-once fused distance+min, MX-fp8 K=128, 2-tile-deep loads --
// grid 256 = 128 b x 2 wh-halves, 512 threads (8 waves), 1 block/CU.
// fp8 A-frags af[4][2] = 64 VGPRs (half of bf16) -> budget for TWO named
// in-flight load sets (ldA/ldB, unroll-2 => compile-time indexing): loads
// issued 2-3 tiles ahead, ~2 tile-bodies of slack before first use.
// x2/p2 stay fp32 (only the cross-term is quantized; err ~1e-9 absolute).
__global__ __launch_bounds__(512, 2)
void proto_min_kernel(const float* __restrict__ xs,
                      const unsigned char* __restrict__ pb8,
                      float* __restrict__ pm) {
    __shared__ unsigned char Xs[2][TILE_B];        // 16 KB
    __shared__ float x2buf[2][8*68 + 8];           // bank-padded

    const int tid  = threadIdx.x;
    const int wv   = tid >> 6;    // 0..7
    const int lane = tid & 63;
    const int lh   = lane >> 4;   // 0..3 (k-group for A/B frags)
    const int lr   = lane & 15;   // 0..15 (row of A / col of B)

    const int b   = blockIdx.x >> 1;
    const int whh = blockIdx.x & 1;

    const float* xb = xs + (size_t)b * (D_K * WH) + whh * WHH;

    // A fragments: fp8(-2p), row = 64wv + 16mf + lr, k = ks*128 + lh*32 + e
    i32x8 af[4][2];
#pragma unroll
    for (int mf = 0; mf < 4; ++mf) {
        const unsigned char* rp = pb8 + (size_t)(64*wv + 16*mf + lr) * D_K + lh*32;
        af[mf][0] = *reinterpret_cast<const i32x8*>(rp);
        af[mf][1] = *reinterpret_cast<const i32x8*>(rp + 128);
    }

    const int n4 = tid & 7;    // col-quad within tile (8 quads x 4 cols)
    const int kq = tid >> 3;   // 0..63  (k-quad; 512 threads cover all 256 k)

    f32x4 rmin[4];
#pragma unroll
    for (int mf = 0; mf < 4; ++mf)
        rmin[mf] = (f32x4){3.0e38f, 3.0e38f, 3.0e38f, 3.0e38f};

    f32x4 ldA[4], ldB[4];   // two named in-flight load sets (16 VGPRs each)

#define LOAD_T(T, LD) do {                                                    \
        int colb = (T) * NT + 4 * n4;                                         \
        if (colb > WHH - 4) colb = WHH - 4;                                   \
        const float* rowp = xb + (size_t)(4*kq) * WH + colb;                  \
        _Pragma("unroll")                                                     \
        for (int r = 0; r < 4; ++r)                                           \
            LD[r] = *reinterpret_cast<const f32x4*>(rowp + r * WH);           \
    } while (0)

// element (n,k): 16B granule kg=k>>4 stored at slot kg ^ ((n ^ (n>>2)) & 7)
#define STAGE_T(DST, LD) do {                                                 \
        f32x4 x2a = {0.f, 0.f, 0.f, 0.f};                                     \
        _Pragma("unroll")                                                     \
        for (int r = 0; r < 4; ++r) {                                         \
            f32x4 v = LD[r];                                                  \
            x2a[0] += v[0]*v[0]; x2a[1] += v[1]*v[1];                         \
            x2a[2] += v[2]*v[2]; x2a[3] += v[3]*v[3];                         \
        }                                                                     \
        _Pragma("unroll")                                                     \
        for (int c = 0; c < 4; ++c) {                                         \
            int n = 4*n4 + c;                                                 \
            int key = (n ^ (n >> 2)) & 7;                                     \
            int u = 0;                                                        \
            u = __builtin_amdgcn_cvt_pk_fp8_f32(LD[0][c], LD[1][c], u, false);\
            u = __builtin_amdgcn_cvt_pk_fp8_f32(LD[2][c], LD[3][c], u, true); \
            int off = n*256 + (((kq >> 2) ^ key) << 4) + ((kq & 3) << 2);     \
            *reinterpret_cast<int*>(&Xs[DST][off]) = u;                       \
        }                                                                     \
        _Pragma("unroll")                                                     \
        for (int c = 0; c < 4; ++c) {                                         \
            x2a[c] += __shfl_xor(x2a[c], 8, 64);                              \
            x2a[c] += __shfl_xor(x2a[c], 16, 64);                             \
            x2a[c] += __shfl_xor(x2a[c], 32, 64);                             \
        }                                                                     \
        if (lane < 8) {                                                       \
            _Pragma("unroll")                                                 \
            for (int c = 0; c < 4; ++c)                                       \
                x2buf[DST][lane*68 + c*8 + wv] = x2a[c];                      \
        }                                                                     \
    } while (0)

// consume buf CUR: x2 init + 16 scaled-MFMA + running min
#define MFMA_TILE(CUR) do {                                                   \
        float x2v[2];                                                         \
        _Pragma("unroll")                                                     \
        for (int nf = 0; nf < 2; ++nf) {                                      \
            int n = 16*nf + lr;                                               \
            const float* xp = &x2buf[CUR][(n >> 2)*68 + (n & 3)*8];           \
            f32x4 q0 = *reinterpret_cast<const f32x4*>(xp);                   \
            f32x4 q1 = *reinterpret_cast<const f32x4*>(xp + 4);               \
            x2v[nf] = ((q0[0]+q0[1]) + (q0[2]+q0[3]))                         \
                    + ((q1[0]+q1[1]) + (q1[2]+q1[3]));                        \
        }                                                                     \
        f32x4 acc[4][2];                                                      \
        _Pragma("unroll")                                                     \
        for (int mf = 0; mf < 4; ++mf) {                                      \
            acc[mf][0] = (f32x4){x2v[0], x2v[0], x2v[0], x2v[0]};             \
            acc[mf][1] = (f32x4){x2v[1], x2v[1], x2v[1], x2v[1]};             \
        }                                                                     \
        __builtin_amdgcn_s_setprio(1);                                        \
        _Pragma("unroll")                                                     \
        for (int ks = 0; ks < 2; ++ks) {                                      \
            i32x8 bfr[2];                                                     \
            _Pragma("unroll")                                                 \
            for (int nf = 0; nf < 2; ++nf) {                                  \
                int n = 16*nf + lr;                                           \
                int key = (n ^ (n >> 2)) & 7;                                 \
                int kg0 = ks*8 + lh*2;                                        \
                i32x4 lo = *reinterpret_cast<const i32x4*>(                   \
                               &Xs[CUR][n*256 + ((kg0 ^ key) << 4)]);         \
                i32x4 hi = *reinterpret_cast<const i32x4*>(                   \
                               &Xs[CUR][n*256 + (((kg0 + 1) ^ key) << 4)]);   \
                bfr[nf] = __builtin_shufflevector(lo, hi, 0,1,2,3,4,5,6,7);   \
            }                                                                 \
            _Pragma("unroll")                                                 \
            for (int mf = 0; mf < 4; ++mf)                                    \
                _Pragma("unroll")                                             \
                for (int nf = 0; nf < 2; ++nf)                                \
                    acc[mf][nf] = __builtin_amdgcn_mfma_scale_f32_16x16x128_f8f6f4( \
                        af[mf][ks], bfr[nf], acc[mf][nf],                     \
                        0, 0, 0, SCALE_ONE, 0, SCALE_ONE);                    \
        }                                                                     \
        __builtin_amdgcn_s_setprio(0);                                        \
        _Pragma("unroll")                                                     \
        for (int mf = 0; mf < 4; ++mf)                                        \
            _Pragma("unroll")                                                 \
            for (int r = 0; r < 4; ++r)                                       \
                rmin[mf][r] = fminf(rmin[mf][r],                              \
                                    fminf(acc[mf][0][r], acc[mf][1][r]));     \
    } while (0)

// body: consume CUR; stage T+1 from LD into NXT; issue T+3 into LD
#define TILE_BODY(T, CUR, NXT, LD) do {                                       \
        MFMA_TILE(CUR);                                                       \
        STAGE_T(NXT, LD);                                                     \
        if ((T) + 3 < NTILES) LOAD_T((T) + 3, LD);                            \
        __syncthreads();                                                      \
    } while (0)

    // prologue: stage tile 0; preload tiles 1 (A) and 2 (B)
    LOAD_T(0, ldA);
    STAGE_T(0, ldA);
    LOAD_T(1, ldA);
    LOAD_T(2, ldB);
    __syncthreads();

    // tiles 0..11 (unroll-2: even tile stages from ldA, odd from ldB)
    for (int tt = 0; tt < 6; ++tt) {
        const int t0 = 2 * tt;
        TILE_BODY(t0,     0, 1, ldA);   // consume buf0, stage t0+1 -> buf1
        TILE_BODY(t0 + 1, 1, 0, ldB);   // consume buf1, stage t0+2 -> buf0
    }

    // peeled final tile 12 (buf 0): no stage/load/barrier
    MFMA_TILE(0);

    // min across the 16 column-lanes (flips only lr bits; lh preserved)
#pragma unroll
    for (int mf = 0; mf < 4; ++mf)
#pragma unroll
        for (int r = 0; r < 4; ++r) {
            float v = rmin[mf][r];
#pragma unroll
            for (int m = 1; m <= 8; m <<= 1)
                v = fminf(v, __shfl_xor(v, m, 64));
            rmin[mf][r] = v;
        }

    if (lr == 0) {
        float* pmw = pm + ((size_t)b * 2 + whh) * P_PAD;
#pragma unroll
        for (int mf = 0; mf < 4; ++mf)
#pragma unroll
            for (int r = 0; r < 4; ++r)
                pmw[64*wv + 16*mf + 4*lh + r] = rmin[mf][r];
    }
#undef LOAD_T
#undef STAGE_T
#undef MFMA_TILE
#undef TILE_BODY
}

// --- combine halves + exp(-sqrt) + tree path products + pa @ ds -----------
__global__ __launch_bounds__(256)
void out_kernel(const float* __restrict__ pm, const float* __restrict__ p2,
                const float* __restrict__ ds, float* __restrict__ out) {
    __shared__ float sim[NLEAF];
    __shared__ float pa[NLEAF];
    int b = blockIdx.x;
    int t = threadIdx.x;
    const float* pm0 = pm + (size_t)b * 2 * P_PAD;
#pragma unroll
    for (int j = 0; j < 2; ++j) {
        int p = t + 256 * j;
        float m = fminf(pm0[p], pm0[P_PAD + p]);
        float sq = m + p2[p];
        sim[p] = expf(-sqrtf(fabsf(sq) + 1e-14f));
    }
    __syncthreads();
#pragma unroll
    for (int j = 0; j < 2; ++j) {
        int leaf = t + 256 * j;
        int node = 0;
        float prod = 1.f;
#pragma unroll
        for (int st = 0; st < TDEPTH; ++st) {
            int bit = (leaf >> (TDEPTH - 1 - st)) & 1;
            float sv = sim[node];
            prod *= bit ? sv : (1.f - sv);
            node = 2 * node + 1 + bit;
        }
        pa[leaf] = prod;
    }
    __syncthreads();
    if (t < C_OUT) {
        float a0 = 0.f, a1 = 0.f, a2 = 0.f, a3 = 0.f;
        for (int l = 0; l < NLEAF; l += 4) {
            a0 += pa[l + 0] * ds[(size_t)(l + 0) * C_OUT + t];
            a1 += pa[l + 1] * ds[(size_t)(l + 1) * C_OUT + t];
            a2 += pa[l + 2] * ds[(size_t)(l + 2) * C_OUT + t];
            a3 += pa[l + 3] * ds[(size_t)(l + 3) * C_OUT + t];
        }
        out[(size_t)b * C_OUT + t] = (a0 + a1) + (a2 + a3);
    }
}

extern "C" void kernel_launch(void* const* d_in, const int* in_sizes, int n_in,
                              void* d_out, int out_size, void* d_ws, size_t ws_size,
                              hipStream_t stream) {
    (void)in_sizes; (void)n_in; (void)out_size; (void)ws_size;
    const float* xs     = (const float*)d_in[0];
    const float* protos = (const float*)d_in[1];
    const float* lp     = (const float*)d_in[2];
    float* out = (float*)d_out;

    char* ws = (char*)d_ws;
    unsigned char* pb8 = (unsigned char*)(ws + WS_PB8);
    float* p2   = (float*)(ws + WS_P2);
    float* dsm  = (float*)(ws + WS_DS);
    float* pm   = (float*)(ws + WS_PM);

    prep2_kernel<<<1024, 64, 0, stream>>>(protos, lp, pb8, p2, dsm);
    proto_min_kernel<<<256, 512, 0, stream>>>(xs, pb8, pm);
    out_kernel<<<128, 256, 0, stream>>>(pm, p2, dsm, out);
}